// Round 6
// baseline (852.255 us; speedup 1.0000x reference)
//
#include <hip/hip_runtime.h>
#include <hip/hip_bf16.h>

#define HD 128
#define RNUM 8
#define KTOT 1152   // 9 * 128
#define SCAN_BS 2048

typedef __attribute__((ext_vector_type(8))) short short8;
typedef __attribute__((ext_vector_type(4))) float float4e;

__device__ __forceinline__ unsigned short f2bf(float f) {
    unsigned int u = __float_as_uint(f);
    u += 0x7fffu + ((u >> 16) & 1u);   // RNE
    return (unsigned short)(u >> 16);
}

// ---------------- small kernels ----------------
__global__ void zero_i(int* __restrict__ p, int n) {
    int g = blockIdx.x * blockDim.x + threadIdx.x;
    if (g < n) p[g] = 0;
}

// ---------------- CSR build: count -> scan -> fill ----------------
__global__ void count_kernel(const int* __restrict__ ei, const int* __restrict__ et,
                             int* __restrict__ cnt, int E, int N) {
    int e = blockIdx.x * blockDim.x + threadIdx.x;
    if (e < E) atomicAdd(&cnt[et[e] * N + ei[E + e]], 1);
}

__global__ void scan1(const int* __restrict__ in, int* __restrict__ out,
                      int* __restrict__ bsum, int n) {
    __shared__ int s[256];
    const int tid = threadIdx.x;
    const int base = blockIdx.x * SCAN_BS + tid * 8;
    int v[8];
    int sum = 0;
#pragma unroll
    for (int j = 0; j < 8; j++) {
        int x = (base + j < n) ? in[base + j] : 0;
        v[j] = sum;
        sum += x;
    }
    s[tid] = sum;
    __syncthreads();
    for (int off = 1; off < 256; off <<= 1) {
        int tv = (tid >= off) ? s[tid - off] : 0;
        __syncthreads();
        if (tid >= off) s[tid] += tv;
        __syncthreads();
    }
    int excl = (tid > 0) ? s[tid - 1] : 0;
    if (tid == 255) bsum[blockIdx.x] = s[255];
#pragma unroll
    for (int j = 0; j < 8; j++)
        if (base + j < n) out[base + j] = v[j] + excl;
}

__global__ void scan2(int* __restrict__ bsum, int nb) {
    __shared__ int s[512];
    const int tid = threadIdx.x;
    s[tid] = (tid < nb) ? bsum[tid] : 0;
    __syncthreads();
    for (int off = 1; off < 512; off <<= 1) {
        int tv = (tid >= off) ? s[tid - off] : 0;
        __syncthreads();
        if (tid >= off) s[tid] += tv;
        __syncthreads();
    }
    if (tid < nb) bsum[tid] = (tid > 0) ? s[tid - 1] : 0;
}

__global__ void scan3(int* __restrict__ out, int* __restrict__ cur,
                      const int* __restrict__ bsum, int n) {
    const int base = blockIdx.x * SCAN_BS + threadIdx.x * 8;
    const int add = bsum[blockIdx.x];
#pragma unroll
    for (int j = 0; j < 8; j++) {
        int i = base + j;
        if (i < n) {
            int v = out[i] + add;
            out[i] = v;
            cur[i] = v;
        }
    }
}

__global__ void fill_kernel(const int* __restrict__ ei, const int* __restrict__ et,
                            int* __restrict__ cur, int* __restrict__ col, int E, int N) {
    int e = blockIdx.x * blockDim.x + threadIdx.x;
    if (e < E) {
        int pos = atomicAdd(&cur[et[e] * N + ei[E + e]], 1);
        col[pos] = ei[e];
    }
}

// ---------------- weight pre-transpose to bf16: WT[f][d] = bf16(W[d][f]) ----------------
__global__ void wt_kernel(const float* __restrict__ W, unsigned short* __restrict__ WT,
                          int nmat) {
    int g = blockIdx.x * blockDim.x + threadIdx.x;
    if (g >= nmat * 16384) return;
    int mat = g >> 14;
    int d = (g >> 7) & 127;
    int f = g & 127;
    WT[mat * 16384 + f * 128 + d] = f2bf(W[g]);
}

// ---------------- agg_all: build bf16 A-panel t[N][1152] ----------------
// wave W in [0, 9N): W = r*N + dst for r<8 -> relation mean; W-8N = dst -> root copy.
template <bool HAS_IDX>
__global__ void agg_all(const int* __restrict__ row_start, const int* __restrict__ col,
                        const int* __restrict__ ids, const float* __restrict__ x,
                        unsigned short* __restrict__ t, int N, int E) {
    long long W = ((long long)blockIdx.x * blockDim.x + threadIdx.x) >> 6;
    if (W >= (long long)9 * N) return;
    int lane = threadIdx.x & 63;

    if (W < (long long)RNUM * N) {
        int seg = (int)W;
        int dst = seg % N;          // W = r*N + dst
        int s0 = row_start[seg];
        int s1 = (seg == RNUM * N - 1) ? E : row_start[seg + 1];
        float2 a = make_float2(0.f, 0.f);
        for (int e = s0; e < s1; e++) {
            int c = col[e];
            if (HAS_IDX) c = ids[c];
            float2 v = *(const float2*)(x + (size_t)c * HD + lane * 2);
            a.x += v.x; a.y += v.y;
        }
        float inv = (s1 > s0) ? (1.0f / (float)(s1 - s0)) : 0.0f;
        unsigned int u = (unsigned int)f2bf(a.x * inv) |
                         ((unsigned int)f2bf(a.y * inv) << 16);
        int r = seg / N;
        *(unsigned int*)(t + (size_t)dst * KTOT + r * HD + lane * 2) = u;
    } else {
        int dst = (int)(W - (long long)RNUM * N);
        int c = HAS_IDX ? ids[dst] : dst;
        float2 v = *(const float2*)(x + (size_t)c * HD + lane * 2);
        unsigned int u = (unsigned int)f2bf(v.x) | ((unsigned int)f2bf(v.y) << 16);
        *(unsigned int*)(t + (size_t)dst * KTOT + 8 * HD + lane * 2) = u;
    }
}

// ---------------- dense bf16 GEMM with fused epilogue ----------------
// C[m,n] = act( sum_k A[m,k]*B[k,n] + bias[n] ),  A: t[N][1152] bf16,
// B: WT[9][128][128] bf16 stored as B^T per source ([n][d]).
template <int ACT>   // 0 = relu, 1 = sigmoid
__launch_bounds__(256)
__global__ void gemm_t(const unsigned short* __restrict__ Abuf,
                       const unsigned short* __restrict__ WT,
                       const float* __restrict__ bias,
                       float* __restrict__ Cout, int N) {
    __shared__ unsigned short As[128 * 128];  // 32 KB
    __shared__ unsigned short Ws[128 * 128];  // 32 KB

    const int tid = threadIdx.x;
    const int block0 = blockIdx.x * 128;
    const int w = tid >> 6;
    const int lane = tid & 63;
    const int ln15 = lane & 15;
    const int quad = lane >> 4;
    const int rowbase = (w & 1) * 64;
    const int colbase = (w >> 1) * 64;

    float4e acc[4][4];
#pragma unroll
    for (int i = 0; i < 4; i++)
#pragma unroll
        for (int j = 0; j < 4; j++)
#pragma unroll
            for (int q = 0; q < 4; q++) acc[i][j][q] = 0.0f;

    for (int s = 0; s < 9; s++) {
        // stage A tile: 128 rows x 128 k bf16, sequential loads, swizzled LDS
#pragma unroll
        for (int i = 0; i < 8; i++) {
            int c = i * 256 + tid;            // chunk of 8 shorts
            int row = c >> 4;
            int ck = c & 15;
            int gr = block0 + row; if (gr >= N) gr = N - 1;
            uint4 v = *(const uint4*)(Abuf + (size_t)gr * KTOT + s * HD + ck * 8);
            *(uint4*)&As[row * 128 + ((ck ^ (row & 15)) << 3)] = v;
        }
        // stage W tile
        {
            const unsigned short* Wsrc = WT + s * 16384;
#pragma unroll
            for (int q = 0; q < 8; q++) {
                int chunk = q * 256 + tid;
                int f = chunk >> 4;
                int c = chunk & 15;
                uint4 v = *(const uint4*)(Wsrc + chunk * 8);
                *(uint4*)&Ws[f * 128 + ((c ^ (f & 15)) << 3)] = v;
            }
        }
        __syncthreads();

#pragma unroll
        for (int k0 = 0; k0 < 4; k0++) {
            short8 af[4], bf[4];
#pragma unroll
            for (int rt = 0; rt < 4; rt++) {
                int m = rowbase + rt * 16 + ln15;
                int ck = k0 * 4 + quad;
                af[rt] = *(const short8*)&As[m * 128 + ((ck ^ (m & 15)) << 3)];
            }
#pragma unroll
            for (int ct = 0; ct < 4; ct++) {
                int n = colbase + ct * 16 + ln15;
                int ck = k0 * 4 + quad;
                bf[ct] = *(const short8*)&Ws[n * 128 + ((ck ^ (n & 15)) << 3)];
            }
#pragma unroll
            for (int rt = 0; rt < 4; rt++)
#pragma unroll
                for (int ct = 0; ct < 4; ct++)
                    acc[rt][ct] = __builtin_amdgcn_mfma_f32_16x16x32_bf16(
                        af[rt], bf[ct], acc[rt][ct], 0, 0, 0);
        }
        __syncthreads();
    }

#pragma unroll
    for (int ct = 0; ct < 4; ct++) {
        int ncol = colbase + ct * 16 + ln15;
        float bv = bias[ncol];
#pragma unroll
        for (int rt = 0; rt < 4; rt++) {
#pragma unroll
            for (int rg = 0; rg < 4; rg++) {
                int rowg = block0 + rowbase + rt * 16 + quad * 4 + rg;
                if (rowg < N) {
                    float v = acc[rt][ct][rg] + bv;
                    v = (ACT == 0) ? fmaxf(v, 0.0f) : (1.0f / (1.0f + expf(-v)));
                    Cout[(size_t)rowg * HD + ncol] = v;
                }
            }
        }
    }
}

// ---------------- fallback: R5 fused layer (used only if ws too small) ----------------
template <bool HAS_IDX, int ACT>
__launch_bounds__(256)
__global__ void rgcn_layer(const int* __restrict__ row_start, const int* __restrict__ col,
                           const int* __restrict__ ids, const float* __restrict__ x,
                           const unsigned short* __restrict__ WT,
                           const float* __restrict__ bias,
                           float* __restrict__ Cout, int N, int E) {
    __shared__ unsigned short As[128 * 128];
    __shared__ unsigned short Ws[128 * 128];

    const int tid = threadIdx.x;
    const int block0 = blockIdx.x * 128;
    const int w = tid >> 6;
    const int lane = tid & 63;
    const int ln15 = lane & 15;
    const int quad = lane >> 4;
    const int rowbase = (w & 1) * 64;
    const int colbase = (w >> 1) * 64;

    float4e acc[4][4];
#pragma unroll
    for (int i = 0; i < 4; i++)
#pragma unroll
        for (int j = 0; j < 4; j++)
#pragma unroll
            for (int q = 0; q < 4; q++) acc[i][j][q] = 0.0f;

    const int srow = tid >> 5;
    const int f4 = (tid & 31) * 4;
    const int sck = f4 >> 3;

    for (int s = 0; s < 9; s++) {
        if (s < RNUM) {
#pragma unroll 1
            for (int p = 0; p < 16; p++) {
                int row = p * 8 + srow;
                int gr = block0 + row;
                float ax = 0.f, ay = 0.f, az = 0.f, aw = 0.f, inv = 0.f;
                if (gr < N) {
                    int seg = s * N + gr;
                    int s0 = row_start[seg];
                    int s1 = (seg == RNUM * N - 1) ? E : row_start[seg + 1];
                    if (s1 > s0) inv = 1.0f / (float)(s1 - s0);
                    for (int e = s0; e < s1; e++) {
                        int c = col[e];
                        if (HAS_IDX) c = ids[c];
                        float4 v = *(const float4*)(x + (size_t)c * HD + f4);
                        ax += v.x; ay += v.y; az += v.z; aw += v.w;
                    }
                }
                int si = row * 128 + ((sck ^ (row & 15)) << 3) + (f4 & 7);
                ushort4 o;
                o.x = f2bf(ax * inv); o.y = f2bf(ay * inv);
                o.z = f2bf(az * inv); o.w = f2bf(aw * inv);
                *(ushort4*)&As[si] = o;
            }
        } else {
#pragma unroll 1
            for (int p = 0; p < 16; p++) {
                int row = p * 8 + srow;
                int gr = block0 + row;
                float4 v = make_float4(0.f, 0.f, 0.f, 0.f);
                if (gr < N) {
                    int c = HAS_IDX ? ids[gr] : gr;
                    v = *(const float4*)(x + (size_t)c * HD + f4);
                }
                int si = row * 128 + ((sck ^ (row & 15)) << 3) + (f4 & 7);
                ushort4 o;
                o.x = f2bf(v.x); o.y = f2bf(v.y); o.z = f2bf(v.z); o.w = f2bf(v.w);
                *(ushort4*)&As[si] = o;
            }
        }
        {
            const unsigned short* Wsrc = WT + s * 16384;
#pragma unroll
            for (int q = 0; q < 8; q++) {
                int chunk = q * 256 + tid;
                int f = chunk >> 4;
                int c = chunk & 15;
                uint4 v = *(const uint4*)(Wsrc + chunk * 8);
                *(uint4*)&Ws[f * 128 + ((c ^ (f & 15)) << 3)] = v;
            }
        }
        __syncthreads();
#pragma unroll
        for (int k0 = 0; k0 < 4; k0++) {
            short8 af[4], bf[4];
#pragma unroll
            for (int rt = 0; rt < 4; rt++) {
                int m = rowbase + rt * 16 + ln15;
                int ck = k0 * 4 + quad;
                af[rt] = *(const short8*)&As[m * 128 + ((ck ^ (m & 15)) << 3)];
            }
#pragma unroll
            for (int ct = 0; ct < 4; ct++) {
                int n = colbase + ct * 16 + ln15;
                int ck = k0 * 4 + quad;
                bf[ct] = *(const short8*)&Ws[n * 128 + ((ck ^ (n & 15)) << 3)];
            }
#pragma unroll
            for (int rt = 0; rt < 4; rt++)
#pragma unroll
                for (int ct = 0; ct < 4; ct++)
                    acc[rt][ct] = __builtin_amdgcn_mfma_f32_16x16x32_bf16(
                        af[rt], bf[ct], acc[rt][ct], 0, 0, 0);
        }
        __syncthreads();
    }

#pragma unroll
    for (int ct = 0; ct < 4; ct++) {
        int ncol = colbase + ct * 16 + ln15;
        float bv = bias[ncol];
#pragma unroll
        for (int rt = 0; rt < 4; rt++) {
#pragma unroll
            for (int rg = 0; rg < 4; rg++) {
                int rowg = block0 + rowbase + rt * 16 + quad * 4 + rg;
                if (rowg < N) {
                    float v = acc[rt][ct][rg] + bv;
                    v = (ACT == 0) ? fmaxf(v, 0.0f) : (1.0f / (1.0f + expf(-v)));
                    Cout[(size_t)rowg * HD + ncol] = v;
                }
            }
        }
    }
}

extern "C" void kernel_launch(void* const* d_in, const int* in_sizes, int n_in,
                              void* d_out, int out_size, void* d_ws, size_t ws_size,
                              hipStream_t stream) {
    const int*   x_ids = (const int*)d_in[0];
    const int*   ei    = (const int*)d_in[1];
    const int*   et    = (const int*)d_in[2];
    const float* emb   = (const float*)d_in[3];
    const float* W1    = (const float*)d_in[4];
    const float* root1 = (const float*)d_in[5];
    const float* b1    = (const float*)d_in[6];
    const float* W2    = (const float*)d_in[7];
    const float* root2 = (const float*)d_in[8];
    const float* b2    = (const float*)d_in[9];

    const int N = in_sizes[0];
    const int E = in_sizes[1] / 2;
    const int NS = RNUM * N;
    float* out = (float*)d_out;

    // ---- workspace ----
    char* ws = (char*)d_ws;
    size_t off = 0;
    int* row_start = (int*)(ws + off); off += (size_t)NS * 4;
    int* cur       = (int*)(ws + off); off += (size_t)NS * 4;
    int* col       = (int*)(ws + off); off += (size_t)E * 4;
    int* bsum      = (int*)(ws + off); off += 4096;
    unsigned short* WT = (unsigned short*)(ws + off); off += (size_t)18 * 16384 * 2;
    float* z       = (float*)(ws + off); off += (size_t)N * HD * 4;
    unsigned short* t = (unsigned short*)(ws + off);
    size_t need_full = off + (size_t)N * KTOT * 2;

    const int scanBlocks = (NS + SCAN_BS - 1) / SCAN_BS;
    const int layerGrid = (N + 127) / 128;

    // ---- CSR build ----
    zero_i<<<(NS + 255) / 256, 256, 0, stream>>>(cur, NS);
    count_kernel<<<(E + 255) / 256, 256, 0, stream>>>(ei, et, cur, E, N);
    scan1<<<scanBlocks, 256, 0, stream>>>(cur, row_start, bsum, NS);
    scan2<<<1, 512, 0, stream>>>(bsum, scanBlocks);
    scan3<<<scanBlocks, 256, 0, stream>>>(row_start, cur, bsum, NS);
    fill_kernel<<<(E + 255) / 256, 256, 0, stream>>>(ei, et, cur, col, E, N);

    // ---- weights -> bf16 transposed ----
    wt_kernel<<<(8 * 16384 + 255) / 256, 256, 0, stream>>>(W1, WT, 8);
    wt_kernel<<<(1 * 16384 + 255) / 256, 256, 0, stream>>>(root1, WT + 8 * 16384, 1);
    wt_kernel<<<(8 * 16384 + 255) / 256, 256, 0, stream>>>(W2, WT + 9 * 16384, 8);
    wt_kernel<<<(1 * 16384 + 255) / 256, 256, 0, stream>>>(root2, WT + 17 * 16384, 1);

    if (ws_size >= need_full) {
        const long long waves = (long long)9 * N;
        const int aggGrid = (int)((waves * 64 + 255) / 256);
        // layer 1
        agg_all<true><<<aggGrid, 256, 0, stream>>>(row_start, col, x_ids, emb, t, N, E);
        gemm_t<0><<<layerGrid, 256, 0, stream>>>(t, WT, b1, z, N);
        // layer 2
        agg_all<false><<<aggGrid, 256, 0, stream>>>(row_start, col, nullptr, z, t, N, E);
        gemm_t<1><<<layerGrid, 256, 0, stream>>>(t, WT + 9 * 16384, b2, out, N);
    } else {
        rgcn_layer<true, 0><<<layerGrid, 256, 0, stream>>>(
            row_start, col, x_ids, emb, WT, b1, z, N, E);
        rgcn_layer<false, 1><<<layerGrid, 256, 0, stream>>>(
            row_start, col, nullptr, z, WT + 9 * 16384, b2, out, N, E);
    }
}

// Round 7
// 754.094 us; speedup vs baseline: 1.1302x; 1.1302x over previous
//
#include <hip/hip_runtime.h>
#include <hip/hip_bf16.h>

#define HD 128
#define RNUM 8
#define SCAN_BS 2048

typedef __attribute__((ext_vector_type(8))) short short8;
typedef __attribute__((ext_vector_type(4))) float float4e;

__device__ __forceinline__ unsigned short f2bf(float f) {
    unsigned int u = __float_as_uint(f);
    u += 0x7fffu + ((u >> 16) & 1u);   // RNE
    return (unsigned short)(u >> 16);
}

// ---------------- small kernels ----------------
__global__ void zero_i(int* __restrict__ p, int n) {
    int g = blockIdx.x * blockDim.x + threadIdx.x;
    if (g < n) p[g] = 0;
}

// ---------------- CSR build: count -> scan -> fill ----------------
__global__ void count_kernel(const int* __restrict__ ei, const int* __restrict__ et,
                             int* __restrict__ cnt, int E, int N) {
    int e = blockIdx.x * blockDim.x + threadIdx.x;
    if (e < E) atomicAdd(&cnt[et[e] * N + ei[E + e]], 1);
}

__global__ void scan1(const int* __restrict__ in, int* __restrict__ out,
                      int* __restrict__ bsum, int n) {
    __shared__ int s[256];
    const int tid = threadIdx.x;
    const int base = blockIdx.x * SCAN_BS + tid * 8;
    int v[8];
    int sum = 0;
#pragma unroll
    for (int j = 0; j < 8; j++) {
        int x = (base + j < n) ? in[base + j] : 0;
        v[j] = sum;
        sum += x;
    }
    s[tid] = sum;
    __syncthreads();
    for (int off = 1; off < 256; off <<= 1) {
        int tv = (tid >= off) ? s[tid - off] : 0;
        __syncthreads();
        if (tid >= off) s[tid] += tv;
        __syncthreads();
    }
    int excl = (tid > 0) ? s[tid - 1] : 0;
    if (tid == 255) bsum[blockIdx.x] = s[255];
#pragma unroll
    for (int j = 0; j < 8; j++)
        if (base + j < n) out[base + j] = v[j] + excl;
}

__global__ void scan2(int* __restrict__ bsum, int nb) {
    __shared__ int s[512];
    const int tid = threadIdx.x;
    s[tid] = (tid < nb) ? bsum[tid] : 0;
    __syncthreads();
    for (int off = 1; off < 512; off <<= 1) {
        int tv = (tid >= off) ? s[tid - off] : 0;
        __syncthreads();
        if (tid >= off) s[tid] += tv;
        __syncthreads();
    }
    if (tid < nb) bsum[tid] = (tid > 0) ? s[tid - 1] : 0;
}

__global__ void scan3(int* __restrict__ out, int* __restrict__ cur,
                      const int* __restrict__ bsum, int n) {
    const int base = blockIdx.x * SCAN_BS + threadIdx.x * 8;
    const int add = bsum[blockIdx.x];
#pragma unroll
    for (int j = 0; j < 8; j++) {
        int i = base + j;
        if (i < n) {
            int v = out[i] + add;
            out[i] = v;
            cur[i] = v;
        }
    }
}

__global__ void fill_kernel(const int* __restrict__ ei, const int* __restrict__ et,
                            int* __restrict__ cur, int* __restrict__ col, int E, int N) {
    int e = blockIdx.x * blockDim.x + threadIdx.x;
    if (e < E) {
        int pos = atomicAdd(&cur[et[e] * N + ei[E + e]], 1);
        col[pos] = ei[e];
    }
}

// ---------------- weight pre-transpose to bf16: WT[f][d] = bf16(W[d][f]) ----------------
__global__ void wt_kernel(const float* __restrict__ W, unsigned short* __restrict__ WT,
                          int nmat) {
    int g = blockIdx.x * blockDim.x + threadIdx.x;
    if (g >= nmat * 16384) return;
    int mat = g >> 14;
    int d = (g >> 7) & 127;
    int f = g & 127;
    WT[mat * 16384 + f * 128 + d] = f2bf(W[g]);
}

// ---------------- agg_chunk: bf16 panel t[cn][8*128] for dst in [c0, c0+cn) ----------------
// wave W: dstLocal = W>>3, r = W&7; one wave per (dst, relation) segment.
template <bool HAS_IDX>
__global__ void agg_chunk(const int* __restrict__ row_start, const int* __restrict__ col,
                          const int* __restrict__ ids, const float* __restrict__ x,
                          unsigned short* __restrict__ t, int N, int E, int c0, int cn) {
    int W = (int)(((long long)blockIdx.x * blockDim.x + threadIdx.x) >> 6);
    if (W >= cn * RNUM) return;
    int lane = threadIdx.x & 63;
    int dstL = W >> 3;
    int r = W & 7;
    int seg = r * N + c0 + dstL;
    int s0 = row_start[seg];
    int s1 = (seg == RNUM * N - 1) ? E : row_start[seg + 1];
    float2 a = make_float2(0.f, 0.f);
    for (int e = s0; e < s1; e++) {
        int c = col[e];
        if (HAS_IDX) c = ids[c];
        float2 v = *(const float2*)(x + (size_t)c * HD + lane * 2);
        a.x += v.x; a.y += v.y;
    }
    float inv = (s1 > s0) ? (1.0f / (float)(s1 - s0)) : 0.0f;
    unsigned int u = (unsigned int)f2bf(a.x * inv) | ((unsigned int)f2bf(a.y * inv) << 16);
    *(unsigned int*)(t + (size_t)dstL * (RNUM * HD) + r * HD + lane * 2) = u;
}

// ---------------- gemm_chunk: C[c0+m,:] = act( sum_{s<8} panel[m,s] @ W_s + x[row]@root + b ) ----------------
template <bool HAS_IDX, int ACT>   // ACT: 0 = relu, 1 = sigmoid
__launch_bounds__(256)
__global__ void gemm_chunk(const unsigned short* __restrict__ Abuf,
                           const float* __restrict__ x, const int* __restrict__ ids,
                           const unsigned short* __restrict__ WT,
                           const float* __restrict__ bias,
                           float* __restrict__ Cout, int N, int c0, int cn) {
    __shared__ unsigned short As[128 * 128];  // 32 KB
    __shared__ unsigned short Ws[128 * 128];  // 32 KB

    const int tid = threadIdx.x;
    const int block0 = blockIdx.x * 128;      // local within chunk
    const int w = tid >> 6;
    const int lane = tid & 63;
    const int ln15 = lane & 15;
    const int quad = lane >> 4;
    const int rowbase = (w & 1) * 64;
    const int colbase = (w >> 1) * 64;

    float4e acc[4][4];
#pragma unroll
    for (int i = 0; i < 4; i++)
#pragma unroll
        for (int j = 0; j < 4; j++)
#pragma unroll
            for (int q = 0; q < 4; q++) acc[i][j][q] = 0.0f;

    for (int s = 0; s < 9; s++) {
        // ---- stage A tile ----
        if (s < RNUM) {
#pragma unroll
            for (int i = 0; i < 8; i++) {
                int c = i * 256 + tid;           // chunk of 8 shorts
                int row = c >> 4;
                int ck = c & 15;
                int rl = block0 + row; if (rl >= cn) rl = cn - 1;
                uint4 v = *(const uint4*)(Abuf + (size_t)rl * (RNUM * HD) + s * HD + ck * 8);
                *(uint4*)&As[row * 128 + ((ck ^ (row & 15)) << 3)] = v;
            }
        } else {
            // root/self term straight from x (gather for layer 1)
#pragma unroll
            for (int i = 0; i < 8; i++) {
                int c = i * 256 + tid;
                int row = c >> 4;
                int ck = c & 15;
                int rl = block0 + row; if (rl >= cn) rl = cn - 1;
                int gnode = c0 + rl;
                int src = HAS_IDX ? ids[gnode] : gnode;
                const float* xp = x + (size_t)src * HD + ck * 8;
                float4 v0 = *(const float4*)(xp);
                float4 v1 = *(const float4*)(xp + 4);
                uint4 o;
                o.x = (unsigned int)f2bf(v0.x) | ((unsigned int)f2bf(v0.y) << 16);
                o.y = (unsigned int)f2bf(v0.z) | ((unsigned int)f2bf(v0.w) << 16);
                o.z = (unsigned int)f2bf(v1.x) | ((unsigned int)f2bf(v1.y) << 16);
                o.w = (unsigned int)f2bf(v1.z) | ((unsigned int)f2bf(v1.w) << 16);
                *(uint4*)&As[row * 128 + ((ck ^ (row & 15)) << 3)] = o;
            }
        }
        // ---- stage W tile ----
        {
            const unsigned short* Wsrc = WT + s * 16384;
#pragma unroll
            for (int q = 0; q < 8; q++) {
                int chunk = q * 256 + tid;
                int f = chunk >> 4;
                int c = chunk & 15;
                uint4 v = *(const uint4*)(Wsrc + chunk * 8);
                *(uint4*)&Ws[f * 128 + ((c ^ (f & 15)) << 3)] = v;
            }
        }
        __syncthreads();

#pragma unroll
        for (int k0 = 0; k0 < 4; k0++) {
            short8 af[4], bf[4];
#pragma unroll
            for (int rt = 0; rt < 4; rt++) {
                int m = rowbase + rt * 16 + ln15;
                int ck = k0 * 4 + quad;
                af[rt] = *(const short8*)&As[m * 128 + ((ck ^ (m & 15)) << 3)];
            }
#pragma unroll
            for (int ct = 0; ct < 4; ct++) {
                int n = colbase + ct * 16 + ln15;
                int ck = k0 * 4 + quad;
                bf[ct] = *(const short8*)&Ws[n * 128 + ((ck ^ (n & 15)) << 3)];
            }
#pragma unroll
            for (int rt = 0; rt < 4; rt++)
#pragma unroll
                for (int ct = 0; ct < 4; ct++)
                    acc[rt][ct] = __builtin_amdgcn_mfma_f32_16x16x32_bf16(
                        af[rt], bf[ct], acc[rt][ct], 0, 0, 0);
        }
        __syncthreads();
    }

#pragma unroll
    for (int ct = 0; ct < 4; ct++) {
        int ncol = colbase + ct * 16 + ln15;
        float bv = bias[ncol];
#pragma unroll
        for (int rt = 0; rt < 4; rt++) {
#pragma unroll
            for (int rg = 0; rg < 4; rg++) {
                int rl = block0 + rowbase + rt * 16 + quad * 4 + rg;
                if (rl < cn) {
                    float v = acc[rt][ct][rg] + bv;
                    v = (ACT == 0) ? fmaxf(v, 0.0f) : (1.0f / (1.0f + expf(-v)));
                    Cout[(size_t)(c0 + rl) * HD + ncol] = v;
                }
            }
        }
    }
}

// ---------------- fallback: R5 fused layer ----------------
template <bool HAS_IDX, int ACT>
__launch_bounds__(256)
__global__ void rgcn_layer(const int* __restrict__ row_start, const int* __restrict__ col,
                           const int* __restrict__ ids, const float* __restrict__ x,
                           const unsigned short* __restrict__ WT,
                           const float* __restrict__ bias,
                           float* __restrict__ Cout, int N, int E) {
    __shared__ unsigned short As[128 * 128];
    __shared__ unsigned short Ws[128 * 128];

    const int tid = threadIdx.x;
    const int block0 = blockIdx.x * 128;
    const int w = tid >> 6;
    const int lane = tid & 63;
    const int ln15 = lane & 15;
    const int quad = lane >> 4;
    const int rowbase = (w & 1) * 64;
    const int colbase = (w >> 1) * 64;

    float4e acc[4][4];
#pragma unroll
    for (int i = 0; i < 4; i++)
#pragma unroll
        for (int j = 0; j < 4; j++)
#pragma unroll
            for (int q = 0; q < 4; q++) acc[i][j][q] = 0.0f;

    const int srow = tid >> 5;
    const int f4 = (tid & 31) * 4;
    const int sck = f4 >> 3;

    for (int s = 0; s < 9; s++) {
        if (s < RNUM) {
#pragma unroll 1
            for (int p = 0; p < 16; p++) {
                int row = p * 8 + srow;
                int gr = block0 + row;
                float ax = 0.f, ay = 0.f, az = 0.f, aw = 0.f, inv = 0.f;
                if (gr < N) {
                    int seg = s * N + gr;
                    int s0 = row_start[seg];
                    int s1 = (seg == RNUM * N - 1) ? E : row_start[seg + 1];
                    if (s1 > s0) inv = 1.0f / (float)(s1 - s0);
                    for (int e = s0; e < s1; e++) {
                        int c = col[e];
                        if (HAS_IDX) c = ids[c];
                        float4 v = *(const float4*)(x + (size_t)c * HD + f4);
                        ax += v.x; ay += v.y; az += v.z; aw += v.w;
                    }
                }
                int si = row * 128 + ((sck ^ (row & 15)) << 3) + (f4 & 7);
                ushort4 o;
                o.x = f2bf(ax * inv); o.y = f2bf(ay * inv);
                o.z = f2bf(az * inv); o.w = f2bf(aw * inv);
                *(ushort4*)&As[si] = o;
            }
        } else {
#pragma unroll 1
            for (int p = 0; p < 16; p++) {
                int row = p * 8 + srow;
                int gr = block0 + row;
                float4 v = make_float4(0.f, 0.f, 0.f, 0.f);
                if (gr < N) {
                    int c = HAS_IDX ? ids[gr] : gr;
                    v = *(const float4*)(x + (size_t)c * HD + f4);
                }
                int si = row * 128 + ((sck ^ (row & 15)) << 3) + (f4 & 7);
                ushort4 o;
                o.x = f2bf(v.x); o.y = f2bf(v.y); o.z = f2bf(v.z); o.w = f2bf(v.w);
                *(ushort4*)&As[si] = o;
            }
        }
        {
            const unsigned short* Wsrc = WT + s * 16384;
#pragma unroll
            for (int q = 0; q < 8; q++) {
                int chunk = q * 256 + tid;
                int f = chunk >> 4;
                int c = chunk & 15;
                uint4 v = *(const uint4*)(Wsrc + chunk * 8);
                *(uint4*)&Ws[f * 128 + ((c ^ (f & 15)) << 3)] = v;
            }
        }
        __syncthreads();
#pragma unroll
        for (int k0 = 0; k0 < 4; k0++) {
            short8 af[4], bf[4];
#pragma unroll
            for (int rt = 0; rt < 4; rt++) {
                int m = rowbase + rt * 16 + ln15;
                int ck = k0 * 4 + quad;
                af[rt] = *(const short8*)&As[m * 128 + ((ck ^ (m & 15)) << 3)];
            }
#pragma unroll
            for (int ct = 0; ct < 4; ct++) {
                int n = colbase + ct * 16 + ln15;
                int ck = k0 * 4 + quad;
                bf[ct] = *(const short8*)&Ws[n * 128 + ((ck ^ (n & 15)) << 3)];
            }
#pragma unroll
            for (int rt = 0; rt < 4; rt++)
#pragma unroll
                for (int ct = 0; ct < 4; ct++)
                    acc[rt][ct] = __builtin_amdgcn_mfma_f32_16x16x32_bf16(
                        af[rt], bf[ct], acc[rt][ct], 0, 0, 0);
        }
        __syncthreads();
    }

#pragma unroll
    for (int ct = 0; ct < 4; ct++) {
        int ncol = colbase + ct * 16 + ln15;
        float bv = bias[ncol];
#pragma unroll
        for (int rt = 0; rt < 4; rt++) {
#pragma unroll
            for (int rg = 0; rg < 4; rg++) {
                int rowg = block0 + rowbase + rt * 16 + quad * 4 + rg;
                if (rowg < N) {
                    float v = acc[rt][ct][rg] + bv;
                    v = (ACT == 0) ? fmaxf(v, 0.0f) : (1.0f / (1.0f + expf(-v)));
                    Cout[(size_t)rowg * HD + ncol] = v;
                }
            }
        }
    }
}

extern "C" void kernel_launch(void* const* d_in, const int* in_sizes, int n_in,
                              void* d_out, int out_size, void* d_ws, size_t ws_size,
                              hipStream_t stream) {
    const int*   x_ids = (const int*)d_in[0];
    const int*   ei    = (const int*)d_in[1];
    const int*   et    = (const int*)d_in[2];
    const float* emb   = (const float*)d_in[3];
    const float* W1    = (const float*)d_in[4];
    const float* root1 = (const float*)d_in[5];
    const float* b1    = (const float*)d_in[6];
    const float* W2    = (const float*)d_in[7];
    const float* root2 = (const float*)d_in[8];
    const float* b2    = (const float*)d_in[9];

    const int N = in_sizes[0];
    const int E = in_sizes[1] / 2;
    const int NS = RNUM * N;
    float* out = (float*)d_out;

    // ---- fixed arenas (~57 MB), then panel (aliases cur: cur only used in CSR build) ----
    char* ws = (char*)d_ws;
    size_t off = 0;
    int* row_start = (int*)(ws + off); off += (size_t)NS * 4;                 // 3.2 MB
    int* col       = (int*)(ws + off); off += (size_t)E * 4;                  // 2.0 MB
    int* bsum      = (int*)(ws + off); off += 4096;
    unsigned short* WT = (unsigned short*)(ws + off); off += (size_t)18 * 16384 * 2;
    float* z       = (float*)(ws + off); off += (size_t)N * HD * 4;           // 51.2 MB
    int* cur       = (int*)(ws + off);                                        // CSR build only
    unsigned short* panel = (unsigned short*)(ws + off);                      // aliases cur

    size_t avail = (ws_size > off) ? (ws_size - off) : 0;
    // cur needs NS*4 bytes; panel needs CH*2048 bytes. Both must fit in avail.
    long long CH_ll = (long long)(avail / (RNUM * HD * 2));
    if (CH_ll > N) CH_ll = N;
    int CH = (int)(CH_ll & ~127LL);     // multiple of 128
    bool ok = (avail >= (size_t)NS * 4) && (CH >= 2048);

    const int scanBlocks = (NS + SCAN_BS - 1) / SCAN_BS;
    const int layerGrid = (N + 127) / 128;

    // ---- CSR build ----
    zero_i<<<(NS + 255) / 256, 256, 0, stream>>>(cur, NS);
    count_kernel<<<(E + 255) / 256, 256, 0, stream>>>(ei, et, cur, E, N);
    scan1<<<scanBlocks, 256, 0, stream>>>(cur, row_start, bsum, NS);
    scan2<<<1, 512, 0, stream>>>(bsum, scanBlocks);
    scan3<<<scanBlocks, 256, 0, stream>>>(row_start, cur, bsum, NS);
    fill_kernel<<<(E + 255) / 256, 256, 0, stream>>>(ei, et, cur, col, E, N);

    // ---- weights -> bf16 transposed: layer1 [0..8], layer2 [9..17] ----
    wt_kernel<<<(8 * 16384 + 255) / 256, 256, 0, stream>>>(W1, WT, 8);
    wt_kernel<<<(1 * 16384 + 255) / 256, 256, 0, stream>>>(root1, WT + 8 * 16384, 1);
    wt_kernel<<<(8 * 16384 + 255) / 256, 256, 0, stream>>>(W2, WT + 9 * 16384, 8);
    wt_kernel<<<(1 * 16384 + 255) / 256, 256, 0, stream>>>(root2, WT + 17 * 16384, 1);

    if (ok) {
        // ---- layer 1: z = relu(agg(emb[ids]) + emb[ids]@root1 + b1) ----
        for (int c0 = 0; c0 < N; c0 += CH) {
            int cn = (N - c0 < CH) ? (N - c0) : CH;
            int aggGrid = (cn * RNUM * 64 + 255) / 256;
            agg_chunk<true><<<aggGrid, 256, 0, stream>>>(row_start, col, x_ids, emb,
                                                         panel, N, E, c0, cn);
            gemm_chunk<true, 0><<<(cn + 127) / 128, 256, 0, stream>>>(
                panel, emb, x_ids, WT, b1, z, N, c0, cn);
        }
        // ---- layer 2: out = sigmoid(agg(z) + z@root2 + b2) ----
        for (int c0 = 0; c0 < N; c0 += CH) {
            int cn = (N - c0 < CH) ? (N - c0) : CH;
            int aggGrid = (cn * RNUM * 64 + 255) / 256;
            agg_chunk<false><<<aggGrid, 256, 0, stream>>>(row_start, col, nullptr, z,
                                                          panel, N, E, c0, cn);
            gemm_chunk<false, 1><<<(cn + 127) / 128, 256, 0, stream>>>(
                panel, z, nullptr, WT + 9 * 16384, b2, out, N, c0, cn);
        }
    } else {
        rgcn_layer<true, 0><<<layerGrid, 256, 0, stream>>>(
            row_start, col, x_ids, emb, WT, b1, z, N, E);
        rgcn_layer<false, 1><<<layerGrid, 256, 0, stream>>>(
            row_start, col, nullptr, z, WT + 9 * 16384, b2, out, N, E);
    }
}